// Round 14
// baseline (44.986 us; speedup 1.0000x reference)
//
#include <hip/hip_runtime.h>
#include <hip/hip_bf16.h>

#define D_IN 12288      // K*G*G
#define HG0 512
#define OUT_N 1024      // HG0+HL

// GEMM1: grid (32 j-tiles, KC1 kc); block = 8 waves; 48 ksteps (1536 d) per block
#define KC1 8
#define KSTEPS_BLK 48
#define KSTEPS_WAVE 6

#define NFOV 384        // foveate blocks (64*12288/8/256), 8 d per thread
#define NW34 256        // W34 conversion blocks (1024*512/8/256)

typedef __attribute__((ext_vector_type(8))) short bf16x8;
typedef __attribute__((ext_vector_type(4))) float f32x4;

static __device__ __forceinline__ short f2bf(float f) {
  __hip_bfloat16 h = __float2bfloat16(f);
  return *reinterpret_cast<short*>(&h);
}

// Fragment-ready layouts (bf16):
//  phis[ks<384][t<4][lane<64][e<8] : lane=(kg*16+lc) holds phi[t*16+lc][ks*32+kg*8+e]
//  hs  [ks<16][t<4][lane<64][e<8]  : lane holds h[t*16+lc][ks*32+kg*8+e]
//  w34s[ot<64][ks<16][lane<64][e<8]: lane holds (W3+W4)[ot*16+lc][ks*32+kg*8+e]

// ---------- Kernel 1: prep = foveate->phis | (W3+W4)->w34s ----------
// fov: one thread = 8 consecutive d of one b -> one coalesced bf16x8 write.
__global__ __launch_bounds__(256) void prep_kernel(
    const float* __restrict__ x, const float* __restrict__ l,
    const float* __restrict__ W3, const float* __restrict__ W4,
    short* __restrict__ phis, short* __restrict__ w34s) {
  int bx = blockIdx.x;

  if (bx >= NFOV) {
    // ---- w34s: g in [0, 65536); reads coalesced, writes fragment-ordered ----
    int g = (bx - NFOV) * 256 + threadIdx.x;
    float4 a0 = *(const float4*)(W3 + (size_t)g * 8);
    float4 a1 = *(const float4*)(W3 + (size_t)g * 8 + 4);
    float4 b0 = *(const float4*)(W4 + (size_t)g * 8);
    float4 b1 = *(const float4*)(W4 + (size_t)g * 8 + 4);
    int r = g >> 6;          // o row (512/8 = 64 chunks per row)
    int c8 = g & 63;
    int ot = r >> 4, lc = r & 15, ks = c8 >> 2, kg = c8 & 3;
    bf16x8 o;
    o[0] = f2bf(a0.x + b0.x); o[1] = f2bf(a0.y + b0.y);
    o[2] = f2bf(a0.z + b0.z); o[3] = f2bf(a0.w + b0.w);
    o[4] = f2bf(a1.x + b1.x); o[5] = f2bf(a1.y + b1.y);
    o[6] = f2bf(a1.z + b1.z); o[7] = f2bf(a1.w + b1.w);
    *(bf16x8*)(w34s + ((((size_t)ot * 16 + ks) * 64) + kg * 16 + lc) * 8) = o;
    return;
  }

  // ---- foveate: g in [0, 98304); d0 = 8-aligned, same k & gy for all 8 ----
  int g = bx * 256 + threadIdx.x;
  int b = g / 1536;                 // 12288/8 = 1536 chunks per b
  int c8 = g - b * 1536;
  int d0 = c8 * 8;
  int k = d0 >> 12;
  int rem = d0 & 4095;
  int gy = rem >> 6, gx0 = rem & 63;   // gx0 multiple of 8

  float lx = l[b * 2 + 0];
  float ly = l[b * 2 + 1];
  int cx = (int)(0.5f * ((lx + 1.0f) * 1024.0f));   // trunc, matches .astype(int32)
  int cy = (int)(0.5f * ((ly + 1.0f) * 1024.0f));

  const float* xb = x + ((size_t)b << 20);
  float v[8];

  if (k == 0) {          // r=4, half=128
    int y0 = cy - 128 + gy * 4;
    int xb0 = cx - 128 + gx0 * 4;
    float s[8] = {0,0,0,0,0,0,0,0};
    #pragma unroll
    for (int dy = 0; dy < 4; ++dy) {
      int yy = y0 + dy;
      if ((unsigned)yy < 1024u) {
        const float* row = xb + ((size_t)yy << 10);
        #pragma unroll
        for (int i = 0; i < 8; ++i)
          #pragma unroll
          for (int dx = 0; dx < 4; ++dx) {
            int xx = xb0 + i * 4 + dx;
            if ((unsigned)xx < 1024u) s[i] += row[xx];
          }
      }
    }
    #pragma unroll
    for (int i = 0; i < 8; ++i) v[i] = s[i] * 0.0625f;
  } else if (k == 1) {   // r=2, half=64
    int y0 = cy - 64 + gy * 2;
    int xb0 = cx - 64 + gx0 * 2;
    float s[8] = {0,0,0,0,0,0,0,0};
    #pragma unroll
    for (int dy = 0; dy < 2; ++dy) {
      int yy = y0 + dy;
      if ((unsigned)yy < 1024u) {
        const float* row = xb + ((size_t)yy << 10);
        #pragma unroll
        for (int i = 0; i < 8; ++i)
          #pragma unroll
          for (int dx = 0; dx < 2; ++dx) {
            int xx = xb0 + i * 2 + dx;
            if ((unsigned)xx < 1024u) s[i] += row[xx];
          }
      }
    }
    #pragma unroll
    for (int i = 0; i < 8; ++i) v[i] = s[i] * 0.25f;
  } else {               // r=1, half=32
    int yy = cy - 32 + gy;
    int xx0 = cx - 32 + gx0;
    const float* row = xb + ((size_t)yy << 10);
    bool yok = (unsigned)yy < 1024u;
    #pragma unroll
    for (int i = 0; i < 8; ++i) {
      int xx = xx0 + i;
      v[i] = (yok && (unsigned)xx < 1024u) ? row[xx] : 0.0f;
    }
  }

  // fragment-ordered coalesced write: d0 8-aligned -> e spans 0..7
  int ks = d0 >> 5, kg = (d0 >> 3) & 3, t = b >> 4, lcb = b & 15;
  bf16x8 o;
  #pragma unroll
  for (int i = 0; i < 8; ++i) o[i] = f2bf(v[i]);
  *(bf16x8*)(phis + (((size_t)ks * 4 + t) * 64 + kg * 16 + lcb) * 8) = o;
}

// ---------- Kernel 2: GEMM1 (coalesced fp32 W1 -> swizzled LDS bf16 frags -> MFMA) ----------
// C[j][b] = sum_d W1[j][d]*phi[b][d] ; partial1[kc][j*64+b]
// grid (32, KC1), block 512 (8 waves). LDS A-layout byte-swizzled by (ks&7)<<4.
__global__ __launch_bounds__(512) void gemm1_kernel(
    const short* __restrict__ phis, const float* __restrict__ W1,
    float* __restrict__ partial1) {
  __shared__ __align__(16) char smem[KSTEPS_BLK * 64 * 8 * 2];   // 48 KB
  float* lds_o = (float*)smem;          // reused for output reduce (32 KB)

  int tid = threadIdx.x;
  int wave = tid >> 6;
  int lane = tid & 63;
  int lc = lane & 15, kg = lane >> 4;
  int jt = blockIdx.x;
  int kc = blockIdx.y;
  int j0 = jt * 16;

  // ---- stage W1 tile (16 rows x 1536 d, fp32, fully coalesced) into LDS frags ----
  {
    int r = tid >> 5;                 // j-row within tile (32 threads/row)
    int c32 = tid & 31;
    const float* row = W1 + (size_t)(j0 + r) * D_IN + (size_t)kc * (KSTEPS_BLK * 32);
    int kgc = (c32 >> 1) & 3;
    int e0 = (c32 & 1) * 4;
    #pragma unroll
    for (int q = 0; q < 12; ++q) {
      int c = (c32 + q * 32) * 4;     // d_local
      int ks = (c32 >> 3) + 4 * q;
      float4 v = *(const float4*)(row + c);
      short4 s4;
      s4.x = f2bf(v.x); s4.y = f2bf(v.y); s4.z = f2bf(v.z); s4.w = f2bf(v.w);
      int byte = ((ks * 64 + kgc * 16 + r) * 16 + e0 * 2) ^ ((ks & 7) << 4);
      *(short4*)(smem + byte) = s4;
    }
  }
  __syncthreads();

  // ---- MFMA: A from swizzled LDS (16B/lane), B from phis (coalesced) ----
  f32x4 acc[4] = {{0,0,0,0},{0,0,0,0},{0,0,0,0},{0,0,0,0}};
  int ksw = wave * KSTEPS_WAVE;
  const short* pbase = phis + (((size_t)kc * KSTEPS_BLK + ksw) * 4 * 64 + lane) * 8;

  #pragma unroll
  for (int s = 0; s < KSTEPS_WAVE; ++s) {
    int ks = ksw + s;
    int abyte = ((ks * 64 + lane) * 16) ^ ((ks & 7) << 4);
    bf16x8 af = *(const bf16x8*)(smem + abyte);
    #pragma unroll
    for (int t = 0; t < 4; ++t) {
      bf16x8 bf = *(const bf16x8*)(pbase + ((size_t)s * 4 + t) * 512);
      acc[t] = __builtin_amdgcn_mfma_f32_16x16x32_bf16(af, bf, acc[t], 0, 0, 0);
    }
  }
  __syncthreads();   // all ds_reads done before overwriting smem

  // stash per-wave results: lds_o[w][j_local = kg*4+r][b = t*16+lc]
  #pragma unroll
  for (int t = 0; t < 4; ++t)
    #pragma unroll
    for (int r = 0; r < 4; ++r)
      lds_o[wave * 1024 + (kg * 4 + r) * 64 + t * 16 + lc] = acc[t][r];
  __syncthreads();

  // reduce 8 waves -> partial1[kc][jt*1024 + e]  (coalesced)
  float* pp = partial1 + (size_t)kc * (HG0 * 64) + (size_t)jt * 1024;
  #pragma unroll
  for (int i = 0; i < 2; ++i) {
    int e = tid + 512 * i;
    float s = 0.0f;
    #pragma unroll
    for (int w = 0; w < 8; ++w) s += lds_o[w * 1024 + e];
    pp[e] = s;
  }
}

// ---------- Kernel 3: reduce split-K + leaky -> hs (fragment-ordered) ----------
__global__ __launch_bounds__(256) void reduce1_kernel(
    const float* __restrict__ partial1, short* __restrict__ hs) {
  int idx = blockIdx.x * 256 + threadIdx.x;   // j*64 + b
  float s = 0.0f;
  #pragma unroll
  for (int kc = 0; kc < KC1; ++kc) s += partial1[(size_t)kc * (HG0 * 64) + idx];
  float v = (s >= 0.0f) ? s : 0.01f * s;
  int j = idx >> 6, b = idx & 63;
  int ks = j >> 5, kg = (j >> 3) & 3, e = j & 7, t = b >> 4, lc = b & 15;
  hs[(((size_t)ks * 4 + t) * 64 + kg * 16 + lc) * 8 + e] = f2bf(v);
}

// ---------- Kernel 4: GEMM2 (MFMA, coalesced fragment loads, + lrelu) ----------
// out[b][o] = lrelu( sum_j h[b][j]*(W3+W4)[o][j] )
__global__ __launch_bounds__(256) void gemm2_kernel(
    const short* __restrict__ hs, const short* __restrict__ w34s,
    float* __restrict__ out) {
  __shared__ float lds[4 * 1024];   // 16KB
  int wave = threadIdx.x >> 6;
  int lane = threadIdx.x & 63;
  int lc = lane & 15, kg = lane >> 4;
  int ot = blockIdx.x;
  int o0 = ot * 16;

  f32x4 acc[4] = {{0,0,0,0},{0,0,0,0},{0,0,0,0},{0,0,0,0}};

  #pragma unroll
  for (int ksl = 0; ksl < 4; ++ksl) {
    int kstep = wave * 4 + ksl;
    bf16x8 bfr = *(const bf16x8*)(w34s + (((size_t)ot * 16 + kstep) * 64 + lane) * 8);
    #pragma unroll
    for (int t = 0; t < 4; ++t) {
      bf16x8 af = *(const bf16x8*)(hs + (((size_t)kstep * 4 + t) * 64 + lane) * 8);
      acc[t] = __builtin_amdgcn_mfma_f32_16x16x32_bf16(af, bfr, acc[t], 0, 0, 0);
    }
  }

  // acc[t][r] = C[b = t*16 + kg*4 + r][o = o0 + lc]
  #pragma unroll
  for (int t = 0; t < 4; ++t)
    #pragma unroll
    for (int r = 0; r < 4; ++r)
      lds[wave * 1024 + t * 256 + kg * 64 + r * 16 + lc] = acc[t][r];
  __syncthreads();

  #pragma unroll
  for (int i = 0; i < 4; ++i) {
    int e = threadIdx.x + 256 * i;
    float s = lds[e] + lds[1024 + e] + lds[2048 + e] + lds[3072 + e];
    float v = (s >= 0.0f) ? s : 0.01f * s;
    int b = ((e >> 8) << 4) + (((e >> 6) & 3) << 2) + ((e >> 4) & 3);
    out[(size_t)b * OUT_N + o0 + (e & 15)] = v;
  }
}

extern "C" void kernel_launch(void* const* d_in, const int* in_sizes, int n_in,
                              void* d_out, int out_size, void* d_ws, size_t ws_size,
                              hipStream_t stream) {
  const float* x  = (const float*)d_in[0];
  const float* l  = (const float*)d_in[1];
  const float* W1 = (const float*)d_in[2];
  const float* W3 = (const float*)d_in[4];
  const float* W4 = (const float*)d_in[5];
  float* out = (float*)d_out;

  char* ws = (char*)d_ws;
  short* phis     = (short*)(ws);                  // 1.5 MB
  float* partial1 = (float*)(ws + (2u << 20));     // 8*512*64*4 = 1 MB
  short* hs       = (short*)(ws + (5u << 20));     // 64 KB
  short* w34s     = (short*)(ws + (6u << 20));     // 1 MB

  prep_kernel<<<dim3(NFOV + NW34), dim3(256), 0, stream>>>(x, l, W3, W4, phis, w34s);
  gemm1_kernel<<<dim3(32, KC1), dim3(512), 0, stream>>>(phis, W1, partial1);
  reduce1_kernel<<<dim3((HG0 * 64) / 256), dim3(256), 0, stream>>>(partial1, hs);
  gemm2_kernel<<<dim3(OUT_N / 16), dim3(256), 0, stream>>>(hs, w34s, out);
}

// Round 15
// 27.667 us; speedup vs baseline: 1.6260x; 1.6260x over previous
//
#include <hip/hip_runtime.h>
#include <hip/hip_bf16.h>

#define D_IN 12288      // K*G*G
#define HG0 512
#define OUT_N 1024      // HG0+HL

// GEMM1: grid (32 j-tiles, KC1 kc); block = 8 waves; 48 ksteps (1536 d) per block
#define KC1 8
#define KSTEPS_BLK 48
#define KSTEPS_WAVE 6

#define NFOV 3072       // foveate blocks (64*12288/256)
#define NW34 256        // W34 conversion blocks (1024*512/8/256)

typedef __attribute__((ext_vector_type(8))) short bf16x8;
typedef __attribute__((ext_vector_type(4))) float f32x4;

static __device__ __forceinline__ short f2bf(float f) {
  __hip_bfloat16 h = __float2bfloat16(f);
  return *reinterpret_cast<short*>(&h);
}

// Fragment-ready layouts (bf16):
//  phis[ks<384][t<4][lane<64][e<8] : lane=(kg*16+lc) holds phi[t*16+lc][ks*32+kg*8+e]
//  hs  [ks<16][t<4][lane<64][e<8]  : lane holds h[t*16+lc][ks*32+kg*8+e]
//  w34s[ot<64][ks<16][lane<64][e<8]: lane holds (W3+W4)[ot*16+lc][ks*32+kg*8+e]

// ---------- Kernel 1: prep = foveate->phis | (W3+W4)->w34s ----------
__global__ __launch_bounds__(256) void prep_kernel(
    const float* __restrict__ x, const float* __restrict__ l,
    const float* __restrict__ W3, const float* __restrict__ W4,
    short* __restrict__ phis, short* __restrict__ w34s) {
  int bx = blockIdx.x;

  if (bx >= NFOV) {
    // ---- w34s: g in [0, 65536); reads coalesced, writes fragment-ordered ----
    int g = (bx - NFOV) * 256 + threadIdx.x;
    float4 a0 = *(const float4*)(W3 + (size_t)g * 8);
    float4 a1 = *(const float4*)(W3 + (size_t)g * 8 + 4);
    float4 b0 = *(const float4*)(W4 + (size_t)g * 8);
    float4 b1 = *(const float4*)(W4 + (size_t)g * 8 + 4);
    int r = g >> 6;          // o row (512/8 = 64 chunks per row)
    int c8 = g & 63;
    int ot = r >> 4, lc = r & 15, ks = c8 >> 2, kg = c8 & 3;
    bf16x8 o;
    o[0] = f2bf(a0.x + b0.x); o[1] = f2bf(a0.y + b0.y);
    o[2] = f2bf(a0.z + b0.z); o[3] = f2bf(a0.w + b0.w);
    o[4] = f2bf(a1.x + b1.x); o[5] = f2bf(a1.y + b1.y);
    o[6] = f2bf(a1.z + b1.z); o[7] = f2bf(a1.w + b1.w);
    *(bf16x8*)(w34s + ((((size_t)ot * 16 + ks) * 64) + kg * 16 + lc) * 8) = o;
    return;
  }

  // ---- foveate ----
  int idx = bx * 256 + threadIdx.x;   // b*D_IN + d
  int b = idx / D_IN;
  int d = idx - b * D_IN;
  int k = d >> 12;
  int rem = d & 4095;
  int gy = rem >> 6, gx = rem & 63;

  float lx = l[b * 2 + 0];
  float ly = l[b * 2 + 1];
  int cx = (int)(0.5f * ((lx + 1.0f) * 1024.0f));   // trunc, matches .astype(int32)
  int cy = (int)(0.5f * ((ly + 1.0f) * 1024.0f));

  const float* xb = x + ((size_t)b << 20);
  float v;

  if (k == 0) {          // r=4, half=128
    int y0 = cy - 128 + gy * 4;
    int x0 = cx - 128 + gx * 4;
    float s = 0.0f;
    #pragma unroll
    for (int dy = 0; dy < 4; ++dy) {
      int yy = y0 + dy;
      if ((unsigned)yy < 1024u) {
        const float* row = xb + ((size_t)yy << 10);
        #pragma unroll
        for (int dx = 0; dx < 4; ++dx) {
          int xx = x0 + dx;
          if ((unsigned)xx < 1024u) s += row[xx];
        }
      }
    }
    v = s * 0.0625f;
  } else if (k == 1) {   // r=2, half=64
    int y0 = cy - 64 + gy * 2;
    int x0 = cx - 64 + gx * 2;
    float s = 0.0f;
    #pragma unroll
    for (int dy = 0; dy < 2; ++dy) {
      int yy = y0 + dy;
      if ((unsigned)yy < 1024u) {
        const float* row = xb + ((size_t)yy << 10);
        #pragma unroll
        for (int dx = 0; dx < 2; ++dx) {
          int xx = x0 + dx;
          if ((unsigned)xx < 1024u) s += row[xx];
        }
      }
    }
    v = s * 0.25f;
  } else {               // r=1, half=32
    int yy = cy - 32 + gy;
    int xx = cx - 32 + gx;
    v = 0.0f;
    if ((unsigned)yy < 1024u && (unsigned)xx < 1024u) v = xb[((size_t)yy << 10) + xx];
  }

  // fragment-ordered phi write
  int ks = d >> 5, kg = (d >> 3) & 3, e = d & 7, t = b >> 4, lcb = b & 15;
  phis[(((size_t)ks * 4 + t) * 64 + kg * 16 + lcb) * 8 + e] = f2bf(v);
}

// ---------- Kernel 2: GEMM1 (coalesced fp32 W1 -> swizzled LDS bf16 frags -> MFMA) ----------
// C[j][b] = sum_d W1[j][d]*phi[b][d] ; partial1[kc][j*64+b]
// grid (32, KC1), block 512 (8 waves). LDS A-layout byte-swizzled by (ks&7)<<4.
__global__ __launch_bounds__(512) void gemm1_kernel(
    const short* __restrict__ phis, const float* __restrict__ W1,
    float* __restrict__ partial1) {
  __shared__ __align__(16) char smem[KSTEPS_BLK * 64 * 8 * 2];   // 48 KB
  float* lds_o = (float*)smem;          // reused for output reduce (32 KB)

  int tid = threadIdx.x;
  int wave = tid >> 6;
  int lane = tid & 63;
  int lc = lane & 15, kg = lane >> 4;
  int jt = blockIdx.x;
  int kc = blockIdx.y;
  int j0 = jt * 16;

  // ---- stage W1 tile (16 rows x 1536 d, fp32, fully coalesced) into LDS frags ----
  {
    int r = tid >> 5;                 // j-row within tile (32 threads/row)
    int c32 = tid & 31;
    const float* row = W1 + (size_t)(j0 + r) * D_IN + (size_t)kc * (KSTEPS_BLK * 32);
    int kgc = (c32 >> 1) & 3;
    int e0 = (c32 & 1) * 4;
    #pragma unroll
    for (int q = 0; q < 12; ++q) {
      int c = (c32 + q * 32) * 4;     // d_local
      int ks = (c32 >> 3) + 4 * q;
      float4 v = *(const float4*)(row + c);
      short4 s4;
      s4.x = f2bf(v.x); s4.y = f2bf(v.y); s4.z = f2bf(v.z); s4.w = f2bf(v.w);
      int byte = ((ks * 64 + kgc * 16 + r) * 16 + e0 * 2) ^ ((ks & 7) << 4);
      *(short4*)(smem + byte) = s4;
    }
  }
  __syncthreads();

  // ---- MFMA: A from swizzled LDS (16B/lane), B from phis (coalesced) ----
  f32x4 acc[4] = {{0,0,0,0},{0,0,0,0},{0,0,0,0},{0,0,0,0}};
  int ksw = wave * KSTEPS_WAVE;
  const short* pbase = phis + (((size_t)kc * KSTEPS_BLK + ksw) * 4 * 64 + lane) * 8;

  #pragma unroll
  for (int s = 0; s < KSTEPS_WAVE; ++s) {
    int ks = ksw + s;
    int abyte = ((ks * 64 + lane) * 16) ^ ((ks & 7) << 4);
    bf16x8 af = *(const bf16x8*)(smem + abyte);
    #pragma unroll
    for (int t = 0; t < 4; ++t) {
      bf16x8 bf = *(const bf16x8*)(pbase + ((size_t)s * 4 + t) * 512);
      acc[t] = __builtin_amdgcn_mfma_f32_16x16x32_bf16(af, bf, acc[t], 0, 0, 0);
    }
  }
  __syncthreads();   // all ds_reads done before overwriting smem

  // stash per-wave results: lds_o[w][j_local = kg*4+r][b = t*16+lc]
  #pragma unroll
  for (int t = 0; t < 4; ++t)
    #pragma unroll
    for (int r = 0; r < 4; ++r)
      lds_o[wave * 1024 + (kg * 4 + r) * 64 + t * 16 + lc] = acc[t][r];
  __syncthreads();

  // reduce 8 waves -> partial1[kc][jt*1024 + e]  (coalesced)
  float* pp = partial1 + (size_t)kc * (HG0 * 64) + (size_t)jt * 1024;
  #pragma unroll
  for (int i = 0; i < 2; ++i) {
    int e = tid + 512 * i;
    float s = 0.0f;
    #pragma unroll
    for (int w = 0; w < 8; ++w) s += lds_o[w * 1024 + e];
    pp[e] = s;
  }
}

// ---------- Kernel 3: reduce split-K + leaky -> hs (fragment-ordered) ----------
__global__ __launch_bounds__(256) void reduce1_kernel(
    const float* __restrict__ partial1, short* __restrict__ hs) {
  int idx = blockIdx.x * 256 + threadIdx.x;   // j*64 + b
  float s = 0.0f;
  #pragma unroll
  for (int kc = 0; kc < KC1; ++kc) s += partial1[(size_t)kc * (HG0 * 64) + idx];
  float v = (s >= 0.0f) ? s : 0.01f * s;
  int j = idx >> 6, b = idx & 63;
  int ks = j >> 5, kg = (j >> 3) & 3, e = j & 7, t = b >> 4, lc = b & 15;
  hs[(((size_t)ks * 4 + t) * 64 + kg * 16 + lc) * 8 + e] = f2bf(v);
}

// ---------- Kernel 4: GEMM2 (MFMA, coalesced fragment loads, + lrelu) ----------
// out[b][o] = lrelu( sum_j h[b][j]*(W3+W4)[o][j] )
__global__ __launch_bounds__(256) void gemm2_kernel(
    const short* __restrict__ hs, const short* __restrict__ w34s,
    float* __restrict__ out) {
  __shared__ float lds[4 * 1024];   // 16KB
  int wave = threadIdx.x >> 6;
  int lane = threadIdx.x & 63;
  int lc = lane & 15, kg = lane >> 4;
  int ot = blockIdx.x;
  int o0 = ot * 16;

  f32x4 acc[4] = {{0,0,0,0},{0,0,0,0},{0,0,0,0},{0,0,0,0}};

  #pragma unroll
  for (int ksl = 0; ksl < 4; ++ksl) {
    int kstep = wave * 4 + ksl;
    bf16x8 bfr = *(const bf16x8*)(w34s + (((size_t)ot * 16 + kstep) * 64 + lane) * 8);
    #pragma unroll
    for (int t = 0; t < 4; ++t) {
      bf16x8 af = *(const bf16x8*)(hs + (((size_t)kstep * 4 + t) * 64 + lane) * 8);
      acc[t] = __builtin_amdgcn_mfma_f32_16x16x32_bf16(af, bfr, acc[t], 0, 0, 0);
    }
  }

  // acc[t][r] = C[b = t*16 + kg*4 + r][o = o0 + lc]
  #pragma unroll
  for (int t = 0; t < 4; ++t)
    #pragma unroll
    for (int r = 0; r < 4; ++r)
      lds[wave * 1024 + t * 256 + kg * 64 + r * 16 + lc] = acc[t][r];
  __syncthreads();

  #pragma unroll
  for (int i = 0; i < 4; ++i) {
    int e = threadIdx.x + 256 * i;
    float s = lds[e] + lds[1024 + e] + lds[2048 + e] + lds[3072 + e];
    float v = (s >= 0.0f) ? s : 0.01f * s;
    int b = ((e >> 8) << 4) + (((e >> 6) & 3) << 2) + ((e >> 4) & 3);
    out[(size_t)b * OUT_N + o0 + (e & 15)] = v;
  }
}

extern "C" void kernel_launch(void* const* d_in, const int* in_sizes, int n_in,
                              void* d_out, int out_size, void* d_ws, size_t ws_size,
                              hipStream_t stream) {
  const float* x  = (const float*)d_in[0];
  const float* l  = (const float*)d_in[1];
  const float* W1 = (const float*)d_in[2];
  const float* W3 = (const float*)d_in[4];
  const float* W4 = (const float*)d_in[5];
  float* out = (float*)d_out;

  char* ws = (char*)d_ws;
  short* phis     = (short*)(ws);                  // 1.5 MB
  float* partial1 = (float*)(ws + (2u << 20));     // 8*512*64*4 = 1 MB
  short* hs       = (short*)(ws + (5u << 20));     // 64 KB
  short* w34s     = (short*)(ws + (6u << 20));     // 1 MB

  prep_kernel<<<dim3(NFOV + NW34), dim3(256), 0, stream>>>(x, l, W3, W4, phis, w34s);
  gemm1_kernel<<<dim3(32, KC1), dim3(512), 0, stream>>>(phis, W1, partial1);
  reduce1_kernel<<<dim3((HG0 * 64) / 256), dim3(256), 0, stream>>>(partial1, hs);
  gemm2_kernel<<<dim3(OUT_N / 16), dim3(256), 0, stream>>>(hs, w34s, out);
}